// Round 2
// baseline (84.909 us; speedup 1.0000x reference)
//
#include <hip/hip_runtime.h>
#include <hip/hip_bf16.h>

typedef __attribute__((ext_vector_type(8))) short short8;
typedef __attribute__((ext_vector_type(4))) float floatx4;

#define L2EPS 1e-12f

__device__ __forceinline__ unsigned short f2bf(float f) {
  union { float f; unsigned u; } c; c.f = f;
  unsigned u = c.u;
  unsigned r = (u + 0x7fffu + ((u >> 16) & 1u)) >> 16;  // RNE
  return (unsigned short)r;
}

__device__ __forceinline__ void gload_lds16(const void* g, void* l) {
  __builtin_amdgcn_global_load_lds(
      (const __attribute__((address_space(1))) unsigned int*)g,
      (__attribute__((address_space(3))) unsigned int*)l,
      16, 0, 0);
}

// ---------------------------------------------------------------------------
// Kernel 1: normalize rows of x (B x 512), emit bf16. One wave per row.
// ---------------------------------------------------------------------------
__global__ __launch_bounds__(256) void xnorm_kernel(const float* __restrict__ x,
                                                    unsigned short* __restrict__ xb) {
  const int lane = threadIdx.x & 63;
  const int wave = threadIdx.x >> 6;
  const int row  = blockIdx.x * 4 + wave;
  const float4* xr = (const float4*)(x + (size_t)row * 512);
  const float4 v0 = xr[lane * 2];
  const float4 v1 = xr[lane * 2 + 1];
  float s = v0.x*v0.x + v0.y*v0.y + v0.z*v0.z + v0.w*v0.w
          + v1.x*v1.x + v1.y*v1.y + v1.z*v1.z + v1.w*v1.w;
#pragma unroll
  for (int off = 32; off > 0; off >>= 1) s += __shfl_xor(s, off);
  const float r = rsqrtf(fmaxf(s, L2EPS));
  short8 o;
  o[0] = (short)f2bf(v0.x * r); o[1] = (short)f2bf(v0.y * r);
  o[2] = (short)f2bf(v0.z * r); o[3] = (short)f2bf(v0.w * r);
  o[4] = (short)f2bf(v1.x * r); o[5] = (short)f2bf(v1.y * r);
  o[6] = (short)f2bf(v1.z * r); o[7] = (short)f2bf(v1.w * r);
  *(short8*)(xb + (size_t)row * 512 + lane * 8) = o;
}

// ---------------------------------------------------------------------------
// Kernel 2: per-row inverse L2 norm of W (D rows of length N). One block/row.
// ---------------------------------------------------------------------------
__global__ __launch_bounds__(256) void wnorm_kernel(const float* __restrict__ W,
                                                    float* __restrict__ rnw, int N) {
  const int d = blockIdx.x;
  const float2* row2 = (const float2*)(W + (size_t)d * N);
  const int n2 = N >> 1;
  float s = 0.f;
  for (int i = threadIdx.x; i < n2; i += 256) {
    const float2 v = row2[i];
    s += v.x * v.x + v.y * v.y;
  }
  if (threadIdx.x == 0 && (N & 1)) {
    const float v = W[(size_t)d * N + (N - 1)];
    s += v * v;
  }
#pragma unroll
  for (int off = 32; off > 0; off >>= 1) s += __shfl_xor(s, off);
  __shared__ float red[4];
  if ((threadIdx.x & 63) == 0) red[threadIdx.x >> 6] = s;
  __syncthreads();
  if (threadIdx.x == 0) {
    const float t = red[0] + red[1] + red[2] + red[3];
    rnw[d] = rsqrtf(fmaxf(t, L2EPS));
  }
}

// ---------------------------------------------------------------------------
// Kernel 3: BT[n][d] = bf16(W[d][n] * rnw[d]), n in [0,Npad) zero-padded.
// ---------------------------------------------------------------------------
__global__ __launch_bounds__(256) void wtrans_kernel(const float* __restrict__ W,
                                                     const float* __restrict__ rnw,
                                                     unsigned short* __restrict__ BT,
                                                     int N, int K) {
  __shared__ unsigned short tile[32][33];
  const int n0 = blockIdx.x * 32;
  const int d0 = blockIdx.y * 32;
  const int tx = threadIdx.x & 31;
  const int ty = threadIdx.x >> 5;  // 0..7
#pragma unroll
  for (int i = 0; i < 4; ++i) {
    const int dl = ty + i * 8;
    const int d = d0 + dl;
    const int n = n0 + tx;
    float v = 0.f;
    if (n < N) v = W[(size_t)d * N + n] * rnw[d];
    tile[tx][dl] = f2bf(v);
  }
  __syncthreads();
#pragma unroll
  for (int i = 0; i < 4; ++i) {
    const int nl = ty + i * 8;
    BT[(size_t)(n0 + nl) * K + d0 + tx] = tile[nl][tx];
  }
}

// ---------------------------------------------------------------------------
// Kernel 4: 256x256 tile, 8 waves (2Mx4N), BK=32, 4 LDS K-tile buffers,
// counted-vmcnt phase-interleaved schedule (T3+T4), setprio (T5).
// K = 512 fixed -> 16 K-tiles. Conflict-free LDS reads (64B rows).
// ---------------------------------------------------------------------------
__global__ __launch_bounds__(512, 2) void gemm_kernel(
    const unsigned short* __restrict__ A,   // (4096,512) bf16
    const unsigned short* __restrict__ BT,  // (6144,512) bf16
    float* __restrict__ C,                  // (4096,N) f32
    int N) {
  __shared__ unsigned short As[4][256 * 32];
  __shared__ unsigned short Bs[4][256 * 32];

  const int tid  = threadIdx.x;
  const int lane = tid & 63;
  const int w    = tid >> 6;   // 0..7
  const int wr   = w >> 2;     // 0..1
  const int wc   = w & 3;      // 0..3

  // bijective XCD swizzle: 384 wg = 8 XCD * 48; column-chunked (B-panel/L2)
  const int bid = blockIdx.x;
  const int swz = (bid & 7) * 48 + (bid >> 3);
  const int by = swz & 15;   // 0..15
  const int bx = swz >> 4;   // 0..23
  const int row0 = by * 256;
  const int col0 = bx * 256;

  floatx4 acc[8][4];
#pragma unroll
  for (int m = 0; m < 8; ++m)
#pragma unroll
    for (int n = 0; n < 4; ++n)
      acc[m][n] = (floatx4){0.f, 0.f, 0.f, 0.f};

  // staging geometry: unit (one matrix K-tile) = 256 rows x 32 cols bf16 = 16KB
  // per thread: 2 x 16B loads. instr i: lin = (w*2+i)*1024 + lane*16 bytes.
  const int j0    = w * 2;
  const int srow0 = j0 * 16 + (lane >> 2);       // +16 for i=1
  const int scol  = (lane & 3) * 8;
  const int ldso  = j0 * 512 + lane * 8;         // LDS elem offset; +512 for i=1
  const unsigned short* Abase = A  + (size_t)row0 * 512 + scol;
  const unsigned short* Bbase = BT + (size_t)col0 * 512 + scol;

#define STAGE_A(t_) do { \
    gload_lds16(Abase + (size_t)srow0 * 512 + (t_) * 32, &As[(t_) & 3][ldso]); \
    gload_lds16(Abase + (size_t)(srow0 + 16) * 512 + (t_) * 32, &As[(t_) & 3][ldso + 512]); \
  } while (0)
#define STAGE_B(t_) do { \
    gload_lds16(Bbase + (size_t)srow0 * 512 + (t_) * 32, &Bs[(t_) & 3][ldso]); \
    gload_lds16(Bbase + (size_t)(srow0 + 16) * 512 + (t_) * 32, &Bs[(t_) & 3][ldso + 512]); \
  } while (0)
#define CFENCE asm volatile("" ::: "memory")

  // frag read geometry (conflict-free: banks = (row&1)*16 + (lane>>4)*4)
  const int ln15  = lane & 15;
  const int kq    = (lane >> 4) * 8;
  const int arow0 = wr * 128 + ln15;
  const int brow0 = wc * 64 + ln15;

  // prologue: stage A0,B0,A1,B1,A2,B2,A3 (7 units, 14 loads); wait A0,B0.
  STAGE_A(0); STAGE_B(0); STAGE_A(1); STAGE_B(1); STAGE_A(2); STAGE_B(2); STAGE_A(3);
  asm volatile("s_waitcnt vmcnt(10)" ::: "memory");
  __builtin_amdgcn_s_barrier();
  CFENCE;

#pragma unroll
  for (int t = 0; t < 16; ++t) {
    const int b = t & 3;
    short8 af[8], bf0, bf1, bf2, bf3;

    // ---- phase odd: load af[0..7], bf0, bf1; stage B(t+3); MFMA n=0,1 ----
#pragma unroll
    for (int m = 0; m < 8; ++m)
      af[m] = *(const short8*)&As[b][(arow0 + m * 16) * 32 + kq];
    bf0 = *(const short8*)&Bs[b][(brow0 + 0 * 16) * 32 + kq];
    bf1 = *(const short8*)&Bs[b][(brow0 + 1 * 16) * 32 + kq];
    if (t + 3 < 16) STAGE_B(t + 3);
    CFENCE;
    __builtin_amdgcn_s_barrier();
    CFENCE;
    __builtin_amdgcn_s_setprio(1);
#pragma unroll
    for (int m = 0; m < 8; ++m) {
      acc[m][0] = __builtin_amdgcn_mfma_f32_16x16x32_bf16(af[m], bf0, acc[m][0], 0, 0, 0);
      acc[m][1] = __builtin_amdgcn_mfma_f32_16x16x32_bf16(af[m], bf1, acc[m][1], 0, 0, 0);
    }
    __builtin_amdgcn_s_setprio(0);
    CFENCE;
    __builtin_amdgcn_s_barrier();
    CFENCE;

    // ---- phase even: load bf2, bf3; stage A(t+4); counted wait; MFMA n=2,3 ----
    bf2 = *(const short8*)&Bs[b][(brow0 + 2 * 16) * 32 + kq];
    bf3 = *(const short8*)&Bs[b][(brow0 + 3 * 16) * 32 + kq];
    if (t + 4 < 16) STAGE_A(t + 4);
    // wait covers next tile's A+B; leaves up to 5 units (10 loads) in flight
    if (t < 12)       asm volatile("s_waitcnt vmcnt(10)" ::: "memory");
    else if (t == 12) asm volatile("s_waitcnt vmcnt(8)"  ::: "memory");
    else if (t == 13) asm volatile("s_waitcnt vmcnt(4)"  ::: "memory");
    else if (t == 14) asm volatile("s_waitcnt vmcnt(0)"  ::: "memory");
    __builtin_amdgcn_s_barrier();
    CFENCE;
    __builtin_amdgcn_s_setprio(1);
#pragma unroll
    for (int m = 0; m < 8; ++m) {
      acc[m][2] = __builtin_amdgcn_mfma_f32_16x16x32_bf16(af[m], bf2, acc[m][2], 0, 0, 0);
      acc[m][3] = __builtin_amdgcn_mfma_f32_16x16x32_bf16(af[m], bf3, acc[m][3], 0, 0, 0);
    }
    __builtin_amdgcn_s_setprio(0);
    CFENCE;
    __builtin_amdgcn_s_barrier();
    CFENCE;
  }

  // epilogue: C/D layout col=lane&15, row=(lane>>4)*4+r
  const int rbase = row0 + wr * 128 + (lane >> 4) * 4;
  const int cbase = col0 + wc * 64 + ln15;
#pragma unroll
  for (int n = 0; n < 4; ++n) {
    const int col = cbase + n * 16;
    if (col < N) {
#pragma unroll
      for (int m = 0; m < 8; ++m) {
        const size_t base = (size_t)(rbase + m * 16) * N + col;
#pragma unroll
        for (int r = 0; r < 4; ++r)
          C[base + (size_t)r * N] = acc[m][n][r];
      }
    }
  }
#undef STAGE_A
#undef STAGE_B
#undef CFENCE
}

// ---------------------------------------------------------------------------
extern "C" void kernel_launch(void* const* d_in, const int* in_sizes, int n_in,
                              void* d_out, int out_size, void* d_ws, size_t ws_size,
                              hipStream_t stream) {
  const float* x = (const float*)d_in[0];
  const float* W = (const float*)d_in[1];
  float* out = (float*)d_out;

  const int D = 512;
  const int B = in_sizes[0] / D;            // 4096
  const int N = in_sizes[1] / D;            // 5994
  const int Npad = ((N + 255) / 256) * 256; // 6144

  char* ws = (char*)d_ws;
  unsigned short* xb  = (unsigned short*)ws;                          // B*D*2
  unsigned short* BTb = (unsigned short*)(ws + (size_t)B * D * 2);    // Npad*D*2
  float* rnw = (float*)(ws + (size_t)B * D * 2 + (size_t)Npad * D * 2);

  xnorm_kernel<<<B / 4, 256, 0, stream>>>(x, xb);
  wnorm_kernel<<<D, 256, 0, stream>>>(W, rnw, N);
  wtrans_kernel<<<dim3(Npad / 32, D / 32), 256, 0, stream>>>(W, rnw, BTb, N, D);
  gemm_kernel<<<(B / 256) * (Npad / 256), 512, 0, stream>>>(xb, BTb, out, N);
}

// Round 3
// 71.610 us; speedup vs baseline: 1.1857x; 1.1857x over previous
//
#include <hip/hip_runtime.h>
#include <hip/hip_bf16.h>

typedef __attribute__((ext_vector_type(8))) short short8;
typedef __attribute__((ext_vector_type(4))) float floatx4;

#define L2EPS 1e-12f

__device__ __forceinline__ unsigned short f2bf(float f) {
  union { float f; unsigned u; } c; c.f = f;
  unsigned u = c.u;
  unsigned r = (u + 0x7fffu + ((u >> 16) & 1u)) >> 16;  // RNE
  return (unsigned short)r;
}

__device__ __forceinline__ void gload_lds16(const void* g, void* l) {
  __builtin_amdgcn_global_load_lds(
      (const __attribute__((address_space(1))) unsigned int*)g,
      (__attribute__((address_space(3))) unsigned int*)l,
      16, 0, 0);
}

// ---------------------------------------------------------------------------
// Kernel 1: normalize rows of x (B x 512), emit bf16. One wave per row.
// ---------------------------------------------------------------------------
__global__ __launch_bounds__(256) void xnorm_kernel(const float* __restrict__ x,
                                                    unsigned short* __restrict__ xb) {
  const int lane = threadIdx.x & 63;
  const int wave = threadIdx.x >> 6;
  const int row  = blockIdx.x * 4 + wave;
  const float4* xr = (const float4*)(x + (size_t)row * 512);
  const float4 v0 = xr[lane * 2];
  const float4 v1 = xr[lane * 2 + 1];
  float s = v0.x*v0.x + v0.y*v0.y + v0.z*v0.z + v0.w*v0.w
          + v1.x*v1.x + v1.y*v1.y + v1.z*v1.z + v1.w*v1.w;
#pragma unroll
  for (int off = 32; off > 0; off >>= 1) s += __shfl_xor(s, off);
  const float r = rsqrtf(fmaxf(s, L2EPS));
  short8 o;
  o[0] = (short)f2bf(v0.x * r); o[1] = (short)f2bf(v0.y * r);
  o[2] = (short)f2bf(v0.z * r); o[3] = (short)f2bf(v0.w * r);
  o[4] = (short)f2bf(v1.x * r); o[5] = (short)f2bf(v1.y * r);
  o[6] = (short)f2bf(v1.z * r); o[7] = (short)f2bf(v1.w * r);
  *(short8*)(xb + (size_t)row * 512 + lane * 8) = o;
}

// ---------------------------------------------------------------------------
// Kernel 2: per-row inverse L2 norm of W (D rows of length N). One block/row.
// ---------------------------------------------------------------------------
__global__ __launch_bounds__(256) void wnorm_kernel(const float* __restrict__ W,
                                                    float* __restrict__ rnw, int N) {
  const int d = blockIdx.x;
  const float2* row2 = (const float2*)(W + (size_t)d * N);
  const int n2 = N >> 1;
  float s = 0.f;
  for (int i = threadIdx.x; i < n2; i += 256) {
    const float2 v = row2[i];
    s += v.x * v.x + v.y * v.y;
  }
  if (threadIdx.x == 0 && (N & 1)) {
    const float v = W[(size_t)d * N + (N - 1)];
    s += v * v;
  }
#pragma unroll
  for (int off = 32; off > 0; off >>= 1) s += __shfl_xor(s, off);
  __shared__ float red[4];
  if ((threadIdx.x & 63) == 0) red[threadIdx.x >> 6] = s;
  __syncthreads();
  if (threadIdx.x == 0) {
    const float t = red[0] + red[1] + red[2] + red[3];
    rnw[d] = rsqrtf(fmaxf(t, L2EPS));
  }
}

// ---------------------------------------------------------------------------
// Kernel 3: BT[n][d] = bf16(W[d][n] * rnw[d]), n in [0,Npad) zero-padded.
// ---------------------------------------------------------------------------
__global__ __launch_bounds__(256) void wtrans_kernel(const float* __restrict__ W,
                                                     const float* __restrict__ rnw,
                                                     unsigned short* __restrict__ BT,
                                                     int N, int K) {
  __shared__ unsigned short tile[32][33];
  const int n0 = blockIdx.x * 32;
  const int d0 = blockIdx.y * 32;
  const int tx = threadIdx.x & 31;
  const int ty = threadIdx.x >> 5;  // 0..7
#pragma unroll
  for (int i = 0; i < 4; ++i) {
    const int dl = ty + i * 8;
    const int d = d0 + dl;
    const int n = n0 + tx;
    float v = 0.f;
    if (n < N) v = W[(size_t)d * N + n] * rnw[d];
    tile[tx][dl] = f2bf(v);
  }
  __syncthreads();
#pragma unroll
  for (int i = 0; i < 4; ++i) {
    const int nl = ty + i * 8;
    BT[(size_t)(n0 + nl) * K + d0 + tx] = tile[nl][tx];
  }
}

// ---------------------------------------------------------------------------
// Kernel 4: 128x128 tile, 4 waves (2x2), BK=32, 4-deep LDS pipeline,
// ONE barrier per K-tile, counted vmcnt(8), XOR chunk-swizzle (both sides),
// 64KB LDS -> 2 blocks/CU resident. K = 512 -> 16 K-tiles.
// ---------------------------------------------------------------------------
#define NT 16

__global__ __launch_bounds__(256, 2) void gemm_kernel(
    const unsigned short* __restrict__ A,   // (4096,512) bf16
    const unsigned short* __restrict__ BT,  // (Npad,512) bf16
    float* __restrict__ C,                  // (4096,N) f32
    int N, int nbx, int nby) {
  __shared__ unsigned short As[4][128 * 32];
  __shared__ unsigned short Bs[4][128 * 32];

  const int tid  = threadIdx.x;
  const int l    = tid & 63;
  const int w    = tid >> 6;   // 0..3
  const int wr   = w >> 1;     // 0..1
  const int wc   = w & 1;      // 0..1

  // XCD swizzle (grid % 8 == 0 guaranteed by launcher: nbx*nby = 1504).
  const int grid = nbx * nby;
  const int bid  = blockIdx.x;
  int swz = bid;
  if ((grid & 7) == 0) swz = (bid & 7) * (grid >> 3) + (bid >> 3);
  const int bx = swz / nby;   // column-major within chunk: B-panel L2 reuse
  const int by = swz % nby;
  const int row0 = by * 128;
  const int col0 = bx * 128;

  floatx4 acc[4][4];
#pragma unroll
  for (int m = 0; m < 4; ++m)
#pragma unroll
    for (int n = 0; n < 4; ++n)
      acc[m][n] = (floatx4){0.f, 0.f, 0.f, 0.f};

  // ---- staging geometry: one instr = 256 thr x 16B = 4KB = 64 rows of 64B.
  // LDS dest linear (lane*16B within wave); SOURCE pre-swizzled:
  // chunk_g = (tid&3) ^ s(row), s(row) = (row>>1)&3 = (tid>>3)&3 here.
  const int srow = tid >> 2;                                  // 0..63
  const int sch  = ((tid & 3) ^ ((tid >> 3) & 3)) * 8;        // elems
  const unsigned short* Ag = A  + (size_t)(row0 + srow) * 512 + sch;
  const unsigned short* Bg = BT + (size_t)(col0 + srow) * 512 + sch;
  const int ldst = srow * 32 + (tid & 3) * 8;                 // elems

#define STAGE(t_) do { \
    gload_lds16(Ag + (t_) * 32,                    &As[(t_) & 3][ldst]); \
    gload_lds16(Ag + (size_t)64 * 512 + (t_) * 32, &As[(t_) & 3][ldst + 2048]); \
    gload_lds16(Bg + (t_) * 32,                    &Bs[(t_) & 3][ldst]); \
    gload_lds16(Bg + (size_t)64 * 512 + (t_) * 32, &Bs[(t_) & 3][ldst + 2048]); \
  } while (0)
#define CFENCE asm volatile("" ::: "memory")

  // ---- frag-read geometry (swizzled chunk; 2 lanes/bank-slot = free) ----
  const int ln15 = l & 15;
  const int qs   = (((l >> 4) ^ ((ln15 >> 1) & 3))) * 8;      // swizzled chunk
  const int ab   = (wr * 64 + ln15) * 32 + qs;                // + m*16*32
  const int bb   = (wc * 64 + ln15) * 32 + qs;                // + n*16*32

  // prologue: 3 tiles in flight (12 loads); wait tile0 (leave 8).
  STAGE(0); STAGE(1); STAGE(2);
  asm volatile("s_waitcnt vmcnt(8)" ::: "memory");
  __builtin_amdgcn_s_barrier();
  CFENCE;

#pragma unroll
  for (int t = 0; t < NT; ++t) {
    const int b = t & 3;
    if (t + 3 < NT) STAGE(t + 3);   // buffer (t-1)&3: all reads done at B_{t-1}
    CFENCE;
    short8 af[4], bf[4];
#pragma unroll
    for (int m = 0; m < 4; ++m) af[m] = *(const short8*)&As[b][ab + m * 512];
#pragma unroll
    for (int n = 0; n < 4; ++n) bf[n] = *(const short8*)&Bs[b][bb + n * 512];
    CFENCE;
    __builtin_amdgcn_s_setprio(1);
#pragma unroll
    for (int m = 0; m < 4; ++m)
#pragma unroll
      for (int n = 0; n < 4; ++n)
        acc[m][n] = __builtin_amdgcn_mfma_f32_16x16x32_bf16(af[m], bf[n], acc[m][n], 0, 0, 0);
    __builtin_amdgcn_s_setprio(0);
    CFENCE;
    // publish tile t+1 (counted: never 0 until the tail)
    if (t < NT - 3)       asm volatile("s_waitcnt vmcnt(8)" ::: "memory");
    else if (t == NT - 3) asm volatile("s_waitcnt vmcnt(4)" ::: "memory");
    else if (t == NT - 2) asm volatile("s_waitcnt vmcnt(0)" ::: "memory");
    if (t < NT - 1) {
      __builtin_amdgcn_s_barrier();
      CFENCE;
    }
  }

  // epilogue: C/D layout col=lane&15, row=(lane>>4)*4+r; n-inner for full lines
  const int rb = row0 + wr * 64 + (l >> 4) * 4;
  const int cb = col0 + wc * 64 + ln15;
#pragma unroll
  for (int m = 0; m < 4; ++m) {
#pragma unroll
    for (int r = 0; r < 4; ++r) {
      const size_t o = (size_t)(rb + m * 16 + r) * N + cb;
#pragma unroll
      for (int n = 0; n < 4; ++n) {
        if (cb + n * 16 < N) C[o + n * 16] = acc[m][n][r];
      }
    }
  }
#undef STAGE
#undef CFENCE
}

// ---------------------------------------------------------------------------
extern "C" void kernel_launch(void* const* d_in, const int* in_sizes, int n_in,
                              void* d_out, int out_size, void* d_ws, size_t ws_size,
                              hipStream_t stream) {
  const float* x = (const float*)d_in[0];
  const float* W = (const float*)d_in[1];
  float* out = (float*)d_out;

  const int D = 512;
  const int B = in_sizes[0] / D;            // 4096
  const int N = in_sizes[1] / D;            // 5994
  const int Npad = ((N + 127) / 128) * 128; // 6016

  char* ws = (char*)d_ws;
  unsigned short* xb  = (unsigned short*)ws;                          // B*D*2
  unsigned short* BTb = (unsigned short*)(ws + (size_t)B * D * 2);    // Npad*D*2
  float* rnw = (float*)(ws + (size_t)B * D * 2 + (size_t)Npad * D * 2);

  const int nby = B / 128;      // 32
  const int nbx = Npad / 128;   // 47

  xnorm_kernel<<<B / 4, 256, 0, stream>>>(x, xb);
  wnorm_kernel<<<D, 256, 0, stream>>>(W, rnw, N);
  wtrans_kernel<<<dim3(Npad / 32, D / 32), 256, 0, stream>>>(W, rnw, BTb, N, D);
  gemm_kernel<<<nbx * nby, 256, 0, stream>>>(xb, BTb, out, N, nbx, nby);
}

// Round 4
// 62.515 us; speedup vs baseline: 1.3582x; 1.1455x over previous
//
#include <hip/hip_runtime.h>
#include <hip/hip_bf16.h>

typedef __attribute__((ext_vector_type(8))) short short8;
typedef __attribute__((ext_vector_type(4))) float floatx4;

#define L2EPS 1e-12f

__device__ __forceinline__ unsigned short f2bf(float f) {
  union { float f; unsigned u; } c; c.f = f;
  unsigned u = c.u;
  unsigned r = (u + 0x7fffu + ((u >> 16) & 1u)) >> 16;  // RNE
  return (unsigned short)r;
}

__device__ __forceinline__ void gload_lds16(const void* g, void* l) {
  __builtin_amdgcn_global_load_lds(
      (const __attribute__((address_space(1))) unsigned int*)g,
      (__attribute__((address_space(3))) unsigned int*)l,
      16, 0, 0);
}

// ---------------------------------------------------------------------------
// Kernel 1: per-row inverse L2 norm of W (D rows of length N). One block/row.
// ---------------------------------------------------------------------------
__global__ __launch_bounds__(256) void wnorm_kernel(const float* __restrict__ W,
                                                    float* __restrict__ rnw, int N) {
  const int d = blockIdx.x;
  const float2* row2 = (const float2*)(W + (size_t)d * N);
  const int n2 = N >> 1;
  float s = 0.f;
  for (int i = threadIdx.x; i < n2; i += 256) {
    const float2 v = row2[i];
    s += v.x * v.x + v.y * v.y;
  }
  if (threadIdx.x == 0 && (N & 1)) {
    const float v = W[(size_t)d * N + (N - 1)];
    s += v * v;
  }
#pragma unroll
  for (int off = 32; off > 0; off >>= 1) s += __shfl_xor(s, off);
  __shared__ float red[4];
  if ((threadIdx.x & 63) == 0) red[threadIdx.x >> 6] = s;
  __syncthreads();
  if (threadIdx.x == 0) {
    const float t = red[0] + red[1] + red[2] + red[3];
    rnw[d] = rsqrtf(fmaxf(t, L2EPS));
  }
}

// ---------------------------------------------------------------------------
// Kernel 2 (fused dispatch): blocks [0,B/4): normalize x rows AND fold rnw
// (A[b,d] = xn[b,d]*rnw[d], bf16). Blocks [B/4, ...): pure transpose-cast
// BT[n][d] = bf16(W[d][n]), n zero-padded to Npad.
// ---------------------------------------------------------------------------
__global__ __launch_bounds__(256) void prep_kernel(const float* __restrict__ x,
                                                   const float* __restrict__ W,
                                                   const float* __restrict__ rnw,
                                                   unsigned short* __restrict__ xb,
                                                   unsigned short* __restrict__ BT,
                                                   int N, int nxb, int nwx) {
  const int bid = blockIdx.x;
  if (bid < nxb) {
    // ---- xnorm part: one wave per row ----
    const int lane = threadIdx.x & 63;
    const int wave = threadIdx.x >> 6;
    const int row  = bid * 4 + wave;
    const float4* xr = (const float4*)(x + (size_t)row * 512);
    const float4 v0 = xr[lane * 2];
    const float4 v1 = xr[lane * 2 + 1];
    float s = v0.x*v0.x + v0.y*v0.y + v0.z*v0.z + v0.w*v0.w
            + v1.x*v1.x + v1.y*v1.y + v1.z*v1.z + v1.w*v1.w;
#pragma unroll
    for (int off = 32; off > 0; off >>= 1) s += __shfl_xor(s, off);
    const float r = rsqrtf(fmaxf(s, L2EPS));
    const float4 w0 = ((const float4*)rnw)[lane * 2];
    const float4 w1 = ((const float4*)rnw)[lane * 2 + 1];
    short8 o;
    o[0] = (short)f2bf(v0.x * r * w0.x); o[1] = (short)f2bf(v0.y * r * w0.y);
    o[2] = (short)f2bf(v0.z * r * w0.z); o[3] = (short)f2bf(v0.w * r * w0.w);
    o[4] = (short)f2bf(v1.x * r * w1.x); o[5] = (short)f2bf(v1.y * r * w1.y);
    o[6] = (short)f2bf(v1.z * r * w1.z); o[7] = (short)f2bf(v1.w * r * w1.w);
    *(short8*)(xb + (size_t)row * 512 + lane * 8) = o;
  } else {
    // ---- wtrans part: 32x32 transpose tiles ----
    __shared__ unsigned short tile[32][33];
    const int wb = bid - nxb;
    const int n0 = (wb % nwx) * 32;
    const int d0 = (wb / nwx) * 32;
    const int tx = threadIdx.x & 31;
    const int ty = threadIdx.x >> 5;  // 0..7
#pragma unroll
    for (int i = 0; i < 4; ++i) {
      const int dl = ty + i * 8;
      const int n = n0 + tx;
      float v = 0.f;
      if (n < N) v = W[(size_t)(d0 + dl) * N + n];
      tile[tx][dl] = f2bf(v);
    }
    __syncthreads();
#pragma unroll
    for (int i = 0; i < 4; ++i) {
      const int nl = ty + i * 8;
      BT[(size_t)(n0 + nl) * 512 + d0 + tx] = tile[nl][tx];
    }
  }
}

// ---------------------------------------------------------------------------
// Kernel 3: GEMM. 128x128 tile, 4 waves (2x2), BK=32, 3-deep LDS pipeline
// (48KB -> 3 blocks/CU), ONE barrier per K-tile, counted vmcnt(4),
// XOR chunk-swizzle on both sides. K = 512 -> 16 K-tiles.
// ---------------------------------------------------------------------------
#define NT 16

__global__ __launch_bounds__(256, 3) void gemm_kernel(
    const unsigned short* __restrict__ A,   // (4096,512) bf16 (x-normalized * rnw)
    const unsigned short* __restrict__ BT,  // (Npad,512) bf16 (W transposed)
    float* __restrict__ C,                  // (4096,N) f32
    int N, int nbx, int nby) {
  __shared__ unsigned short As[3][128 * 32];
  __shared__ unsigned short Bs[3][128 * 32];

  const int tid  = threadIdx.x;
  const int l    = tid & 63;
  const int w    = tid >> 6;   // 0..3
  const int wr   = w >> 1;     // 0..1
  const int wc   = w & 1;      // 0..1

  // XCD swizzle (grid % 8 == 0: nbx*nby = 1504).
  const int grid = nbx * nby;
  const int bid  = blockIdx.x;
  int swz = bid;
  if ((grid & 7) == 0) swz = (bid & 7) * (grid >> 3) + (bid >> 3);
  const int bx = swz / nby;   // column-major within chunk: B-panel L2 reuse
  const int by = swz % nby;
  const int row0 = by * 128;
  const int col0 = bx * 128;

  floatx4 acc[4][4];
#pragma unroll
  for (int m = 0; m < 4; ++m)
#pragma unroll
    for (int n = 0; n < 4; ++n)
      acc[m][n] = (floatx4){0.f, 0.f, 0.f, 0.f};

  // staging: one instr = 256 thr x 16B = 4KB = 64 rows of 64B.
  // LDS dest linear; SOURCE chunk pre-swizzled: chunk_g = (tid&3) ^ ((row>>1)&3).
  const int srow = tid >> 2;                                  // 0..63
  const int sch  = ((tid & 3) ^ ((tid >> 3) & 3)) * 8;        // elems
  const unsigned short* Ag = A  + (size_t)(row0 + srow) * 512 + sch;
  const unsigned short* Bg = BT + (size_t)(col0 + srow) * 512 + sch;
  const int ldst = srow * 32 + (tid & 3) * 8;                 // elems

#define STAGE(t_) do { \
    gload_lds16(Ag + (t_) * 32,                    &As[(t_) % 3][ldst]); \
    gload_lds16(Ag + (size_t)64 * 512 + (t_) * 32, &As[(t_) % 3][ldst + 2048]); \
    gload_lds16(Bg + (t_) * 32,                    &Bs[(t_) % 3][ldst]); \
    gload_lds16(Bg + (size_t)64 * 512 + (t_) * 32, &Bs[(t_) % 3][ldst + 2048]); \
  } while (0)
#define CFENCE asm volatile("" ::: "memory")

  // frag-read geometry (swizzled chunk; 2 lanes/bank-slot = free)
  const int ln15 = l & 15;
  const int qs   = (((l >> 4) ^ ((ln15 >> 1) & 3))) * 8;      // swizzled chunk
  const int ab   = (wr * 64 + ln15) * 32 + qs;                // + m*16*32
  const int bb   = (wc * 64 + ln15) * 32 + qs;                // + n*16*32

  // prologue: 2 tiles in flight (8 loads); wait tile0 (leave 4).
  STAGE(0); STAGE(1);
  asm volatile("s_waitcnt vmcnt(4)" ::: "memory");
  __builtin_amdgcn_s_barrier();
  CFENCE;

#pragma unroll
  for (int t = 0; t < NT; ++t) {
    const int b = t % 3;
    if (t + 2 < NT) STAGE(t + 2);   // writes buf (t-1)%3: reads done at barrier t-1
    CFENCE;
    short8 af[4], bf[4];
#pragma unroll
    for (int m = 0; m < 4; ++m) af[m] = *(const short8*)&As[b][ab + m * 512];
#pragma unroll
    for (int n = 0; n < 4; ++n) bf[n] = *(const short8*)&Bs[b][bb + n * 512];
    CFENCE;
    __builtin_amdgcn_s_setprio(1);
#pragma unroll
    for (int m = 0; m < 4; ++m)
#pragma unroll
      for (int n = 0; n < 4; ++n)
        acc[m][n] = __builtin_amdgcn_mfma_f32_16x16x32_bf16(af[m], bf[n], acc[m][n], 0, 0, 0);
    __builtin_amdgcn_s_setprio(0);
    CFENCE;
    // publish tile t+1 (counted: never 0 until the tail)
    if (t < NT - 2)       asm volatile("s_waitcnt vmcnt(4)" ::: "memory");
    else if (t == NT - 2) asm volatile("s_waitcnt vmcnt(0)" ::: "memory");
    if (t < NT - 1) {
      __builtin_amdgcn_s_barrier();
      CFENCE;
    }
  }

  // epilogue: C/D layout col=lane&15, row=(lane>>4)*4+r; n-inner
  const int rb = row0 + wr * 64 + (l >> 4) * 4;
  const int cb = col0 + wc * 64 + ln15;
#pragma unroll
  for (int m = 0; m < 4; ++m) {
#pragma unroll
    for (int r = 0; r < 4; ++r) {
      const size_t o = (size_t)(rb + m * 16 + r) * N + cb;
#pragma unroll
      for (int n = 0; n < 4; ++n) {
        if (cb + n * 16 < N) C[o + n * 16] = acc[m][n][r];
      }
    }
  }
#undef STAGE
#undef CFENCE
}

// ---------------------------------------------------------------------------
extern "C" void kernel_launch(void* const* d_in, const int* in_sizes, int n_in,
                              void* d_out, int out_size, void* d_ws, size_t ws_size,
                              hipStream_t stream) {
  const float* x = (const float*)d_in[0];
  const float* W = (const float*)d_in[1];
  float* out = (float*)d_out;

  const int D = 512;
  const int B = in_sizes[0] / D;            // 4096
  const int N = in_sizes[1] / D;            // 5994
  const int Npad = ((N + 127) / 128) * 128; // 6016

  char* ws = (char*)d_ws;
  unsigned short* xb  = (unsigned short*)ws;                          // B*D*2
  unsigned short* BTb = (unsigned short*)(ws + (size_t)B * D * 2);    // Npad*D*2
  float* rnw = (float*)(ws + (size_t)B * D * 2 + (size_t)Npad * D * 2);

  const int nby = B / 128;      // 32
  const int nbx = Npad / 128;   // 47
  const int nxb = B / 4;        // 1024 xnorm blocks
  const int nwx = Npad / 32;    // 188 wtrans tiles per d-stripe
  const int nwb = nwx * (D / 32);  // 3008 wtrans blocks

  wnorm_kernel<<<D, 256, 0, stream>>>(W, rnw, N);
  prep_kernel<<<nxb + nwb, 256, 0, stream>>>(x, W, rnw, xb, BTb, N, nxb, nwx);
  gemm_kernel<<<nbx * nby, 256, 0, stream>>>(xb, BTb, out, N, nbx, nby);
}